// Round 1
// baseline (1847.181 us; speedup 1.0000x reference)
//
#include <hip/hip_runtime.h>

// Problem constants
#define NPOS   158   // 64 query + 94 doc token positions per batch
#define NCH    32    // chains (windows) per block: w=0 query, w=1..31 docs
#define EPITCH 136   // shorts per e row (128 + 8 pad -> 272B, breaks bank stride)
#define HPITCH 264   // shorts per h row (256 + 8 pad -> 528B)
#define WP_ELEMS (2*64*12*64*8)  // [dir][nt 64][ks 12][lane 64][j 8] bf16

typedef __attribute__((ext_vector_type(8))) short  short8;
typedef __attribute__((ext_vector_type(4))) short  short4v;
typedef __attribute__((ext_vector_type(4))) float  float4v;

__device__ __forceinline__ unsigned short f2bf(float x){
  unsigned int u = __builtin_bit_cast(unsigned int, x);
  u += 0x7FFFu + ((u >> 16) & 1u);           // round-to-nearest-even
  return (unsigned short)(u >> 16);
}
__device__ __forceinline__ float fsig(float x){
  return 1.0f/(1.0f + __expf(-x));
}
__device__ __forceinline__ float ftanh(float x){
  float ax = fabsf(x);
  float e  = __expf(-2.0f*ax);
  float r  = (1.0f - e)/(1.0f + e);
  return (x < 0.0f) ? -r : r;
}

// ---------------------------------------------------------------------------
// Pack W = [k (128 rows); rk (256 rows)] (per dir) into MFMA B-fragment lane
// order: element j of lane l for tile (nt, ks) = W[k = ks*32+(l>>4)*8+j][col =
// nt*16+(l&15)], so the recurrent kernel's B loads are coalesced dwordx4.
// ---------------------------------------------------------------------------
__global__ void prepack(const float* __restrict__ kf, const float* __restrict__ rkf,
                        const float* __restrict__ kb, const float* __restrict__ rkb,
                        unsigned short* __restrict__ wpack){
  int idx  = blockIdx.x*256 + threadIdx.x;      // exactly WP_ELEMS threads
  int j    = idx & 7;
  int lane = (idx >> 3) & 63;
  int rest = idx >> 9;                          // d*768 + nt*12 + ks
  int ks   = rest % 12;
  int nt   = (rest / 12) & 63;
  int d    = rest / (12*64);
  int k    = ks*32 + (lane >> 4)*8 + j;
  int col  = nt*16 + (lane & 15);
  const float* Kp  = d ? kb  : kf;
  const float* RKp = d ? rkb : rkf;
  float v = (k < 128) ? Kp[k*1024 + col] : RKp[(k-128)*1024 + col];
  wpack[idx] = f2bf(v);
}

// ---------------------------------------------------------------------------
// Persistent recurrent kernel: block = (batch, direction), 32 chains, 64 steps.
// Per step: Z[32,1024] = [e_t | h] @ Wpacked + bias via mfma_f32_16x16x32_bf16,
// then fp32 peephole-LSTM gates in-register (state never leaves the block).
// Wave wv owns hidden units j in [32*wv, 32*wv+32): all 4 gates for those j
// land in its own accumulators -> no LDS round-trip for Z.
// ---------------------------------------------------------------------------
__launch_bounds__(512, 2)
__global__ void lstm_rec(const int* __restrict__ inputs, const float* __restrict__ emb,
                         const unsigned short* __restrict__ wpack,
                         const float* __restrict__ bias_f, const float* __restrict__ wci_f,
                         const float* __restrict__ wcf_f,  const float* __restrict__ wco_f,
                         const float* __restrict__ bias_b, const float* __restrict__ wci_b,
                         const float* __restrict__ wcf_b,  const float* __restrict__ wco_b,
                         float* __restrict__ h_out)
{
  __shared__ int tok[NPOS];
  __shared__ __align__(16) short e_lds[NPOS*EPITCH];   // 43.0 KB bf16 embeddings
  __shared__ __align__(16) short h_lds[NCH*HPITCH];    // 16.9 KB bf16 h state

  const int tid  = threadIdx.x;
  const int lane = tid & 63;
  const int wv   = tid >> 6;        // wave 0..7
  const int lc   = lane & 15;
  const int q    = lane >> 4;       // quarter-wave
  const int bat  = blockIdx.x & 127;
  const int dir  = blockIdx.x >> 7;

  // stage tokens, zero h
  for (int p = tid; p < NPOS; p += 512) tok[p] = inputs[bat*NPOS + p];
  for (int i = tid; i < NCH*HPITCH; i += 512) h_lds[i] = 0;
  __syncthreads();

  // stage all 158 position embeddings as bf16 (row p = position p of batch)
  for (int idx = tid; idx < NPOS*32; idx += 512){
    int p = idx >> 5, c4 = (idx & 31) << 2;
    float4v v = *(const float4v*)(emb + (long)tok[p]*128 + c4);
    short4v s;
    s[0] = (short)f2bf(v[0]); s[1] = (short)f2bf(v[1]);
    s[2] = (short)f2bf(v[2]); s[3] = (short)f2bf(v[3]);
    *(short4v*)&e_lds[p*EPITCH + c4] = s;
  }

  const float* bias = dir ? bias_b : bias_f;
  const float* wci  = dir ? wci_b  : wci_f;
  const float* wcf  = dir ? wcf_b  : wcf_f;
  const float* wco  = dir ? wco_b  : wco_f;

  // per-lane constants: bias per acc tile (col = lane-fixed), peephole per j
  float biasr[8];
  #pragma unroll
  for (int g = 0; g < 4; ++g)
    #pragma unroll
    for (int tj = 0; tj < 2; ++tj)
      biasr[g*2+tj] = bias[g*256 + wv*32 + tj*16 + lc];
  float wcir[2], wcfr[2], wcor[2];
  #pragma unroll
  for (int tj = 0; tj < 2; ++tj){
    int j = wv*32 + tj*16 + lc;
    wcir[tj] = wci[j]; wcfr[tj] = wcf[j]; wcor[tj] = wco[j];
  }

  // fp32 state held by the lane that owns (chain m, hidden j) per C/D layout
  float hreg[2][4][2], creg[2][4][2];
  #pragma unroll
  for (int mt = 0; mt < 2; ++mt)
    #pragma unroll
    for (int r = 0; r < 4; ++r)
      #pragma unroll
      for (int tj = 0; tj < 2; ++tj){ hreg[mt][r][tj] = 0.f; creg[mt][r][tj] = 0.f; }

  const short8* W = (const short8*)(wpack) + (long)dir*64*12*64;

  __syncthreads();   // e_lds / h_lds ready

  const int m0 = lc, m1 = 16 + lc;   // A-fragment rows (chains) for the 2 M-tiles

  for (int s = 0; s < 64; ++s){
    const int t  = dir ? (63 - s) : s;                 // backward runs reversed
    const int p0 = (m0 == 0) ? t : 63 + m0 + t;        // chain w position at t
    const int p1 = 63 + m1 + t;

    float4v acc[2][8];                                  // [mtile][g*2+tj]
    #pragma unroll
    for (int n = 0; n < 8; ++n){
      float bv = biasr[n];
      acc[0][n] = (float4v){bv,bv,bv,bv};
      acc[1][n] = acc[0][n];
    }

    #pragma unroll
    for (int ks = 0; ks < 12; ++ks){                    // K = 384 = 128 e + 256 h
      short8 a0, a1;
      if (ks < 4){
        a0 = *(const short8*)&e_lds[p0*EPITCH + ks*32 + q*8];
        a1 = *(const short8*)&e_lds[p1*EPITCH + ks*32 + q*8];
      } else {
        a0 = *(const short8*)&h_lds[m0*HPITCH + (ks-4)*32 + q*8];
        a1 = *(const short8*)&h_lds[m1*HPITCH + (ks-4)*32 + q*8];
      }
      #pragma unroll
      for (int g = 0; g < 4; ++g){
        #pragma unroll
        for (int tj = 0; tj < 2; ++tj){
          int nt = g*16 + wv*2 + tj;                    // col block = g*256+32wv+16tj
          short8 bfrag = W[(nt*12 + ks)*64 + lane];     // coalesced dwordx4
          int n = g*2 + tj;
          acc[0][n] = __builtin_amdgcn_mfma_f32_16x16x32_bf16(a0, bfrag, acc[0][n], 0, 0, 0);
          acc[1][n] = __builtin_amdgcn_mfma_f32_16x16x32_bf16(a1, bfrag, acc[1][n], 0, 0, 0);
        }
      }
    }

    __syncthreads();   // everyone done reading h_lds for this step

    // gates: C/D layout row = q*4+r (chain), col = lc (hidden j within tile)
    #pragma unroll
    for (int mt = 0; mt < 2; ++mt){
      #pragma unroll
      for (int r = 0; r < 4; ++r){
        int m = mt*16 + q*4 + r;
        int p = (m == 0) ? t : 63 + m + t;
        bool msk = (tok[p] != 0);                       // Keras masking
        #pragma unroll
        for (int tj = 0; tj < 2; ++tj){
          float zi = acc[mt][0+tj][r];
          float zf = acc[mt][2+tj][r];
          float zc = acc[mt][4+tj][r];
          float zo = acc[mt][6+tj][r];
          float c0 = creg[mt][r][tj];
          float ig = fsig(zi + c0*wcir[tj]);
          float fg = fsig(zf + c0*wcfr[tj]);
          float cn = fg*c0 + ig*ftanh(zc);
          float og = fsig(zo + cn*wcor[tj]);
          float hn = og*ftanh(cn);
          float hv = msk ? hn : hreg[mt][r][tj];        // carry through masked
          float cv = msk ? cn : c0;
          hreg[mt][r][tj] = hv;
          creg[mt][r][tj] = cv;
          h_lds[m*HPITCH + wv*32 + tj*16 + lc] = (short)f2bf(hv);
        }
      }
    }
    __syncthreads();   // h writes visible before next step's MFMA reads
  }

  // final h (fp32) -> workspace [dir][bat][chain][hidden]
  #pragma unroll
  for (int mt = 0; mt < 2; ++mt)
    #pragma unroll
    for (int r = 0; r < 4; ++r){
      int m = mt*16 + q*4 + r;
      #pragma unroll
      for (int tj = 0; tj < 2; ++tj){
        int j = wv*32 + tj*16 + lc;
        h_out[(((long)dir*128 + bat)*32 + m)*256 + j] = hreg[mt][r][tj];
      }
    }
}

// ---------------------------------------------------------------------------
// h_avg = 0.5(h_f + h_b); cos = |q.d|/(|q||d|); softmax over 31 docs.
// ---------------------------------------------------------------------------
__global__ void finalize(const float* __restrict__ h_out, float* __restrict__ out){
  __shared__ float hav[32*256];
  __shared__ float dotl[32], sql[32];
  const int bat = blockIdx.x;
  const int tid = threadIdx.x;
  const float* hf = h_out + (long)bat*8192;
  const float* hb = h_out + (long)(128 + bat)*8192;
  for (int i = tid; i < 8192; i += 256) hav[i] = 0.5f*(hf[i] + hb[i]);
  __syncthreads();
  const int lane = tid & 63, wv = tid >> 6;
  for (int n = wv; n < 32; n += 4){
    float s1 = 0.f, s2 = 0.f;
    for (int j = lane; j < 256; j += 64){
      float a  = hav[n*256 + j];
      float qv = hav[j];
      s1 += a*qv; s2 += a*a;
    }
    #pragma unroll
    for (int off = 32; off; off >>= 1){
      s1 += __shfl_down(s1, off);
      s2 += __shfl_down(s2, off);
    }
    if (lane == 0){ dotl[n] = s1; sql[n] = s2; }
  }
  __syncthreads();
  if (wv == 0){
    float cosv = -1e30f;
    if (lane < 31)
      cosv = fabsf(dotl[lane+1]) / (sqrtf(sql[0]) * sqrtf(sql[lane+1]));
    float mx = cosv;
    #pragma unroll
    for (int off = 32; off; off >>= 1) mx = fmaxf(mx, __shfl_xor(mx, off));
    float e = (lane < 31) ? __expf(cosv - mx) : 0.f;
    float sum = e;
    #pragma unroll
    for (int off = 32; off; off >>= 1) sum += __shfl_xor(sum, off);
    if (lane < 31) out[bat*31 + lane] = e / sum;
  }
}

extern "C" void kernel_launch(void* const* d_in, const int* in_sizes, int n_in,
                              void* d_out, int out_size, void* d_ws, size_t ws_size,
                              hipStream_t stream) {
  const int*   inputs = (const int*)  d_in[0];
  const float* emb    = (const float*)d_in[1];
  const float* k_f    = (const float*)d_in[2];
  const float* rk_f   = (const float*)d_in[3];
  const float* b_f    = (const float*)d_in[4];
  const float* wci_f  = (const float*)d_in[5];
  const float* wcf_f  = (const float*)d_in[6];
  const float* wco_f  = (const float*)d_in[7];
  const float* k_b    = (const float*)d_in[8];
  const float* rk_b   = (const float*)d_in[9];
  const float* b_b    = (const float*)d_in[10];
  const float* wci_b  = (const float*)d_in[11];
  const float* wcf_b  = (const float*)d_in[12];
  const float* wco_b  = (const float*)d_in[13];

  unsigned short* wpack = (unsigned short*)d_ws;                    // 1.50 MB
  float* h_out = (float*)((char*)d_ws + (size_t)WP_ELEMS*2);        // 8.39 MB

  prepack<<<WP_ELEMS/256, 256, 0, stream>>>(k_f, rk_f, k_b, rk_b, wpack);
  lstm_rec<<<256, 512, 0, stream>>>(inputs, emb, wpack,
                                    b_f, wci_f, wcf_f, wco_f,
                                    b_b, wci_b, wcf_b, wco_b, h_out);
  finalize<<<128, 256, 0, stream>>>(h_out, (float*)d_out);
}

// Round 2
// 1303.717 us; speedup vs baseline: 1.4169x; 1.4169x over previous
//
#include <hip/hip_runtime.h>

// Problem constants
#define NPOS   158   // 64 query + 94 doc token positions per batch
#define NCH    32    // chains (windows) per block
#define EPITCH 136   // shorts per staged emb row (128 + 8 pad)
#define HPITCH 264   // shorts per h row (256 + 8 pad)

// workspace layout (bytes)
#define RKP_SHORTS (2*64*8*512)            // rk packed: [dir][nt64][ks8][lane64][j8]
#define KP_SHORTS  (2*64*4*512)            // k  packed: [dir][nt64][ks4][lane64][j8]
#define XZ_HALFS   ((size_t)2*128*158*1024)
#define OFF_KP     ((size_t)RKP_SHORTS*2)                 // 1,048,576
#define OFF_XZ     (OFF_KP + (size_t)KP_SHORTS*2)         // 1,572,864
#define OFF_HOUT   (OFF_XZ + XZ_HALFS*2)                  // 84,410,368

typedef __attribute__((ext_vector_type(8))) short    short8;
typedef __attribute__((ext_vector_type(4))) short    short4v;
typedef __attribute__((ext_vector_type(4))) float    float4v;
typedef __attribute__((ext_vector_type(8))) _Float16 half8;

__device__ __forceinline__ unsigned short f2bf(float x){
  unsigned int u = __builtin_bit_cast(unsigned int, x);
  u += 0x7FFFu + ((u >> 16) & 1u);           // round-to-nearest-even
  return (unsigned short)(u >> 16);
}
__device__ __forceinline__ float fsig(float x){
  return 1.0f/(1.0f + __expf(-x));
}
__device__ __forceinline__ float ftanh(float x){
  float ax = fabsf(x);
  float e  = __expf(-2.0f*ax);
  float r  = (1.0f - e)/(1.0f + e);
  return (x < 0.0f) ? -r : r;
}

// ---------------------------------------------------------------------------
// Pack rk (256x1024) and k (128x1024) per dir into MFMA B-fragment lane order:
// element j of lane l for tile (nt,ks) = W[k = ks*32+(l>>4)*8+j][col = nt*16+(l&15)].
// ---------------------------------------------------------------------------
__global__ void prepack(const float* __restrict__ kf, const float* __restrict__ rkf,
                        const float* __restrict__ kb, const float* __restrict__ rkb,
                        unsigned short* __restrict__ rkp, unsigned short* __restrict__ kp){
  int idx = blockIdx.x*256 + threadIdx.x;
  if (idx < RKP_SHORTS){
    int j = idx & 7, lane = (idx>>3)&63, ks = (idx>>9)&7, nt = (idx>>12)&63, d = idx>>18;
    const float* RK = d ? rkb : rkf;
    int k   = ks*32 + (lane>>4)*8 + j;
    int col = nt*16 + (lane&15);
    rkp[idx] = f2bf(RK[k*1024 + col]);
  } else {
    int i2 = idx - RKP_SHORTS;
    int j = i2 & 7, lane = (i2>>3)&63, ks = (i2>>9)&3, nt = (i2>>11)&63, d = i2>>17;
    const float* K = d ? kb : kf;
    int k   = ks*32 + (lane>>4)*8 + j;
    int col = nt*16 + (lane&15);
    kp[i2] = f2bf(K[k*1024 + col]);
  }
}

// ---------------------------------------------------------------------------
// xz[dir][bat][pos][1024] (fp16, wave-permuted inner layout) = emb @ k + bias.
// Inner layout: [... pos][wv 8][lc 16][n 8] where n = gate*2 + tj, so the
// recurrent kernel's lane (wv,lc) reads its 8 acc-init values as ONE 16B load.
// Grid: 128 bat x 2 dir x 5 pos-tiles of 32.
// ---------------------------------------------------------------------------
__launch_bounds__(512)
__global__ void xzgemm(const int* __restrict__ inputs, const float* __restrict__ emb,
                       const unsigned short* __restrict__ kpack,
                       const float* __restrict__ b_f, const float* __restrict__ b_b,
                       _Float16* __restrict__ xz){
  __shared__ int tokp[32];
  __shared__ __align__(16) short e_lds[32*EPITCH];
  const int bid = blockIdx.x;
  const int pt  = bid % 5;
  const int bd  = bid / 5;
  const int bat = bd & 127, dir = bd >> 7;
  const int tid = threadIdx.x, lane = tid & 63, wv = tid >> 6;
  const int lc  = lane & 15, q = lane >> 4;

  for (int i = tid; i < 32*EPITCH; i += 512) e_lds[i] = 0;
  if (tid < 32){
    int p = pt*32 + tid;
    tokp[tid] = (p < NPOS) ? inputs[bat*NPOS + p] : 0;
  }
  __syncthreads();
  for (int idx = tid; idx < 32*32; idx += 512){
    int i = idx >> 5, c4 = (idx & 31) << 2;
    int p = pt*32 + i;
    if (p < NPOS){
      float4v v = *(const float4v*)(emb + (long)tokp[i]*128 + c4);
      short4v s;
      s[0]=(short)f2bf(v[0]); s[1]=(short)f2bf(v[1]);
      s[2]=(short)f2bf(v[2]); s[3]=(short)f2bf(v[3]);
      *(short4v*)&e_lds[i*EPITCH + c4] = s;
    }
  }
  __syncthreads();

  const float* bias = dir ? b_b : b_f;
  float4v acc[2][8];
  #pragma unroll
  for (int g = 0; g < 4; ++g)
    #pragma unroll
    for (int tj = 0; tj < 2; ++tj){
      float bv = bias[g*256 + wv*32 + tj*16 + lc];
      acc[0][g*2+tj] = (float4v){bv,bv,bv,bv};
      acc[1][g*2+tj] = acc[0][g*2+tj];
    }

  const short8* KP = (const short8*)kpack + (long)dir*64*4*64;
  #pragma unroll
  for (int ks = 0; ks < 4; ++ks){
    short8 a0 = *(const short8*)&e_lds[lc*EPITCH + ks*32 + q*8];
    short8 a1 = *(const short8*)&e_lds[(16+lc)*EPITCH + ks*32 + q*8];
    #pragma unroll
    for (int n = 0; n < 8; ++n){
      int g = n >> 1, tj = n & 1;
      int nt = g*16 + wv*2 + tj;
      short8 b = KP[(nt*4 + ks)*64 + lane];
      acc[0][n] = __builtin_amdgcn_mfma_f32_16x16x32_bf16(a0, b, acc[0][n], 0, 0, 0);
      acc[1][n] = __builtin_amdgcn_mfma_f32_16x16x32_bf16(a1, b, acc[1][n], 0, 0, 0);
    }
  }

  _Float16* xzb = xz + ((long)(dir*128 + bat))*NPOS*1024;
  #pragma unroll
  for (int mt = 0; mt < 2; ++mt)
    #pragma unroll
    for (int r = 0; r < 4; ++r){
      int row = mt*16 + q*4 + r;
      int p = pt*32 + row;
      if (p < NPOS){
        half8 hv;
        #pragma unroll
        for (int n = 0; n < 8; ++n) hv[n] = (_Float16)acc[mt][n][r];
        *(half8*)(xzb + (long)p*1024 + wv*128 + lc*8) = hv;
      }
    }
}

// ---------------------------------------------------------------------------
// Recurrent kernel: block = (batch, dir), 32 chains, 64 steps, K=256 (h only).
// acc init = precomputed xz (one 16B load per (mt,r)); B-fragments register
// double-buffered (all 8 next-ks loads in flight under current 16 MFMAs);
// h double-buffered in LDS -> ONE __syncthreads per step.
// ---------------------------------------------------------------------------
__launch_bounds__(512, 2)
__global__ void lstm_rec(const int* __restrict__ inputs, const _Float16* __restrict__ xz,
                         const unsigned short* __restrict__ rkpack,
                         const float* __restrict__ wci_f, const float* __restrict__ wcf_f,
                         const float* __restrict__ wco_f,
                         const float* __restrict__ wci_b, const float* __restrict__ wcf_b,
                         const float* __restrict__ wco_b,
                         float* __restrict__ h_out)
{
  __shared__ int tok[NPOS];
  __shared__ __align__(16) short h_lds[2][NCH*HPITCH];   // 2 x 16.9 KB bf16

  const int tid  = threadIdx.x;
  const int lane = tid & 63;
  const int wv   = tid >> 6;
  const int lc   = lane & 15;
  const int q    = lane >> 4;
  const int bat  = blockIdx.x & 127;
  const int dir  = blockIdx.x >> 7;

  for (int p = tid; p < NPOS; p += 512) tok[p] = inputs[bat*NPOS + p];
  for (int i = tid; i < NCH*HPITCH; i += 512) h_lds[0][i] = 0;

  const float* wci = dir ? wci_b : wci_f;
  const float* wcf = dir ? wcf_b : wcf_f;
  const float* wco = dir ? wco_b : wco_f;
  float wcir[2], wcfr[2], wcor[2];
  #pragma unroll
  for (int tj = 0; tj < 2; ++tj){
    int j = wv*32 + tj*16 + lc;
    wcir[tj] = wci[j]; wcfr[tj] = wcf[j]; wcor[tj] = wco[j];
  }

  float hreg[2][4][2], creg[2][4][2];
  #pragma unroll
  for (int mt = 0; mt < 2; ++mt)
    #pragma unroll
    for (int r = 0; r < 4; ++r)
      #pragma unroll
      for (int tj = 0; tj < 2; ++tj){ hreg[mt][r][tj] = 0.f; creg[mt][r][tj] = 0.f; }

  const short8*   RK  = (const short8*)rkpack + (long)dir*64*8*64;
  const _Float16* xzb = xz + ((long)(dir*128 + bat))*NPOS*1024 + wv*128 + lc*8;

  __syncthreads();

  const int m0 = lc, m1 = 16 + lc;

  for (int s = 0; s < 64; ++s){
    const int t  = dir ? (63 - s) : s;
    const int rb = s & 1, wb = rb ^ 1;

    // acc init from xz (8 coalesced 16B loads; deepest in flight)
    float4v acc[2][8];
    #pragma unroll
    for (int mt = 0; mt < 2; ++mt)
      #pragma unroll
      for (int r = 0; r < 4; ++r){
        int m = mt*16 + q*4 + r;
        int p = (m == 0) ? t : 63 + m + t;
        half8 hv = *(const half8*)(xzb + (long)p*1024);
        #pragma unroll
        for (int n = 0; n < 8; ++n) acc[mt][n][r] = (float)hv[n];
      }

    // B-fragment register double-buffer over K=256 (8 ks slices)
    short8 bb[2][8];
    #pragma unroll
    for (int n = 0; n < 8; ++n){
      int g = n >> 1, tj = n & 1, nt = g*16 + wv*2 + tj;
      bb[0][n] = RK[(nt*8 + 0)*64 + lane];
    }
    #pragma unroll
    for (int ks = 0; ks < 8; ++ks){
      int cb = ks & 1;
      if (ks < 7){
        #pragma unroll
        for (int n = 0; n < 8; ++n){
          int g = n >> 1, tj = n & 1, nt = g*16 + wv*2 + tj;
          bb[cb^1][n] = RK[(nt*8 + ks + 1)*64 + lane];
        }
      }
      short8 a0 = *(const short8*)&h_lds[rb][m0*HPITCH + ks*32 + q*8];
      short8 a1 = *(const short8*)&h_lds[rb][m1*HPITCH + ks*32 + q*8];
      #pragma unroll
      for (int n = 0; n < 8; ++n){
        acc[0][n] = __builtin_amdgcn_mfma_f32_16x16x32_bf16(a0, bb[cb][n], acc[0][n], 0, 0, 0);
        acc[1][n] = __builtin_amdgcn_mfma_f32_16x16x32_bf16(a1, bb[cb][n], acc[1][n], 0, 0, 0);
      }
    }

    // gates: C/D layout row = q*4+r (chain), col = lc
    #pragma unroll
    for (int mt = 0; mt < 2; ++mt){
      #pragma unroll
      for (int r = 0; r < 4; ++r){
        int m = mt*16 + q*4 + r;
        int p = (m == 0) ? t : 63 + m + t;
        bool msk = (tok[p] != 0);
        #pragma unroll
        for (int tj = 0; tj < 2; ++tj){
          float zi = acc[mt][0+tj][r];
          float zf = acc[mt][2+tj][r];
          float zc = acc[mt][4+tj][r];
          float zo = acc[mt][6+tj][r];
          float c0 = creg[mt][r][tj];
          float ig = fsig(zi + c0*wcir[tj]);
          float fg = fsig(zf + c0*wcfr[tj]);
          float cn = fg*c0 + ig*ftanh(zc);
          float og = fsig(zo + cn*wcor[tj]);
          float hn = og*ftanh(cn);
          float hv = msk ? hn : hreg[mt][r][tj];
          float cv = msk ? cn : c0;
          hreg[mt][r][tj] = hv;
          creg[mt][r][tj] = cv;
          h_lds[wb][m*HPITCH + wv*32 + tj*16 + lc] = (short)f2bf(hv);
        }
      }
    }
    __syncthreads();   // one barrier per step (double-buffered h)
  }

  #pragma unroll
  for (int mt = 0; mt < 2; ++mt)
    #pragma unroll
    for (int r = 0; r < 4; ++r){
      int m = mt*16 + q*4 + r;
      #pragma unroll
      for (int tj = 0; tj < 2; ++tj){
        int j = wv*32 + tj*16 + lc;
        h_out[(((long)dir*128 + bat)*32 + m)*256 + j] = hreg[mt][r][tj];
      }
    }
}

// ---------------------------------------------------------------------------
// h_avg = 0.5(h_f + h_b); cos = |q.d|/(|q||d|); softmax over 31 docs.
// ---------------------------------------------------------------------------
__global__ void finalize(const float* __restrict__ h_out, float* __restrict__ out){
  __shared__ float hav[32*256];
  __shared__ float dotl[32], sql[32];
  const int bat = blockIdx.x;
  const int tid = threadIdx.x;
  const float* hf = h_out + (long)bat*8192;
  const float* hb = h_out + (long)(128 + bat)*8192;
  for (int i = tid; i < 8192; i += 256) hav[i] = 0.5f*(hf[i] + hb[i]);
  __syncthreads();
  const int lane = tid & 63, wv = tid >> 6;
  for (int n = wv; n < 32; n += 4){
    float s1 = 0.f, s2 = 0.f;
    for (int j = lane; j < 256; j += 64){
      float a  = hav[n*256 + j];
      float qv = hav[j];
      s1 += a*qv; s2 += a*a;
    }
    #pragma unroll
    for (int off = 32; off; off >>= 1){
      s1 += __shfl_down(s1, off);
      s2 += __shfl_down(s2, off);
    }
    if (lane == 0){ dotl[n] = s1; sql[n] = s2; }
  }
  __syncthreads();
  if (wv == 0){
    float cosv = -1e30f;
    if (lane < 31)
      cosv = fabsf(dotl[lane+1]) / (sqrtf(sql[0]) * sqrtf(sql[lane+1]));
    float mx = cosv;
    #pragma unroll
    for (int off = 32; off; off >>= 1) mx = fmaxf(mx, __shfl_xor(mx, off));
    float e = (lane < 31) ? __expf(cosv - mx) : 0.f;
    float sum = e;
    #pragma unroll
    for (int off = 32; off; off >>= 1) sum += __shfl_xor(sum, off);
    if (lane < 31) out[bat*31 + lane] = e / sum;
  }
}

extern "C" void kernel_launch(void* const* d_in, const int* in_sizes, int n_in,
                              void* d_out, int out_size, void* d_ws, size_t ws_size,
                              hipStream_t stream) {
  const int*   inputs = (const int*)  d_in[0];
  const float* emb    = (const float*)d_in[1];
  const float* k_f    = (const float*)d_in[2];
  const float* rk_f   = (const float*)d_in[3];
  const float* b_f    = (const float*)d_in[4];
  const float* wci_f  = (const float*)d_in[5];
  const float* wcf_f  = (const float*)d_in[6];
  const float* wco_f  = (const float*)d_in[7];
  const float* k_b    = (const float*)d_in[8];
  const float* rk_b   = (const float*)d_in[9];
  const float* b_b    = (const float*)d_in[10];
  const float* wci_b  = (const float*)d_in[11];
  const float* wcf_b  = (const float*)d_in[12];
  const float* wco_b  = (const float*)d_in[13];

  unsigned short* rkp  = (unsigned short*)d_ws;
  unsigned short* kp   = (unsigned short*)((char*)d_ws + OFF_KP);
  _Float16*       xzp  = (_Float16*)     ((char*)d_ws + OFF_XZ);
  float*          hout = (float*)        ((char*)d_ws + OFF_HOUT);

  prepack<<<(RKP_SHORTS + KP_SHORTS)/256, 256, 0, stream>>>(k_f, rk_f, k_b, rk_b, rkp, kp);
  xzgemm <<<128*2*5, 512, 0, stream>>>(inputs, emb, kp, b_f, b_b, xzp);
  lstm_rec<<<256, 512, 0, stream>>>(inputs, xzp, rkp,
                                    wci_f, wcf_f, wco_f,
                                    wci_b, wcf_b, wco_b, hout);
  finalize<<<128, 256, 0, stream>>>(hout, (float*)d_out);
}